// Round 6
// baseline (267.619 us; speedup 1.0000x reference)
//
#include <hip/hip_runtime.h>
#include <cstdint>
#include <cstddef>

#define Kn 32
#define Bn 512
#define Tn 2048
#define CH 128              // chunk length
#define NC (Tn / CH)        // 16 chunks per batch row
#define GP 4                // gold partials per batch row (1 per wave)
#define MMB (Bn * 2)        // 1024 mm blocks: wave w of block (b,g) owns chunks (8g+2w, 8g+2w+1)
#define GB  Bn              // 512 gold blocks, 4 waves each
#define START 30
#define STOP 31
#define LN2F 0.69314718055994530942f
#define QS 16               // steps per staged LDS quarter
#define QF (QS * Kn)        // 512 floats = 2 KiB per buffer

typedef __attribute__((ext_vector_type(8))) short bf16x8;   // 8 bf16 (4 VGPRs)
typedef __attribute__((ext_vector_type(16))) float f32x16;  // MFMA 32x32 accum
typedef __attribute__((ext_vector_type(2))) float f32x2;    // packed f32 pair

union BF8 { bf16x8 v; unsigned u[4]; };

// pack two non-negative f32 -> bf16x2, round-toward-zero: single v_perm.
__device__ __forceinline__ unsigned pk2z(float lo, float hi) {
  return __builtin_amdgcn_perm(__float_as_uint(hi), __float_as_uint(lo),
                               0x07060302u);
}

__device__ __forceinline__ float bcast32(float v, int idx) {
  return __shfl(v, idx, 32);
}

// v_permlane32_swap_b32: swaps a's lanes 32..63 with b's lanes 0..31.
__device__ __forceinline__ void plswap(unsigned& a, unsigned& b) {
  asm("v_permlane32_swap_b32 %0, %1" : "+v"(a), "+v"(b));
}

// ---------------------------------------------------------------------------
// Fused phase 1, DUAL-CHAIN waves, SOURCE-INTERLEAVED.
// R5 post-mortem: dual-chain gave only -7% because each mm carried 4 inline
// asm statements (scheduler barriers) -> [A-work|fence][B-work|fence]; the
// chains serialized (dual-step 1004cy == 2x single-step 502cy). Fix: mm2
// interleaves the chains BY HAND (exp/frags interleaved, MFMAs A1,B1,A2,B2,
// packs interleaved) and fuses all 8 permlane swaps into ONE asm block at
// the end -> one barrier per dual-step, B's issue fills A's MFMA C-dep
// latency even if the compiler preserves source order exactly.
// Worst-case timeline ~330-400cy/dual-step (issue floor ~330) -> fused
// ~50-65us. Per-chain math bit-identical (pure reordering of independent
// ops) -> absmax 0.0.
// P_new = diag(exp(feat_t))*exp(trans) * P_old via 2x mfma_f32_32x32x16_bf16.
// D layout: row=(r&3)+8*(r>>2)+4h, col=lane&31.
// Tripwire: WRITE_SIZE >> 17.5MB means spill -> revert to (256,3).
// ---------------------------------------------------------------------------
__global__ __launch_bounds__(256, 4) void crf_fused(
    const float* __restrict__ feats, const float* __restrict__ trans,
    const int* __restrict__ tags, const int* __restrict__ lens,
    float* __restrict__ pmats, float* __restrict__ poffs,
    float* __restrict__ gold_part) {
  __shared__ float lds[4][2][2][QF];   // 32 KiB: [wave][chain][dbuf][512]
  const int wid = threadIdx.x >> 6;
  const int lane = threadIdx.x & 63;

  if (blockIdx.x < MMB) {
    const int b = blockIdx.x >> 1;
    const int g = blockIdx.x & 1;
    const int c0 = 8 * g + 2 * wid;                 // 0,2,..,14
    const int len = lens[b];
    const int n0 = min(max(len - c0 * CH, 0), CH);
    const int n1 = min(max(len - (c0 + 1) * CH, 0), CH);  // n1>0 => n0==CH
    if (n0 == 0) return;

    const int m = lane & 31;
    const int h = lane >> 5;

    // E fragments (f32 pairs) with 2^-7 static renorm folded in.
    f32x2 e1[4], e2[4];
    {
      const float* tr = trans + m * Kn + 8 * h;
#pragma unroll
      for (int j = 0; j < 4; ++j) {
        e1[j] = (f32x2){__expf(tr[2 * j]) * 0.0078125f,
                        __expf(tr[2 * j + 1]) * 0.0078125f};
        e2[j] = (f32x2){__expf(tr[16 + 2 * j]) * 0.0078125f,
                        __expf(tr[16 + 2 * j + 1]) * 0.0078125f};
      }
    }
    // identity B-fragments, index-free init (bf16 1.0 = 0x3F80)
    unsigned buA[8], buB[8];
    {
      const int j1 = m - 8 * h;
      const int j2 = m - 16 - 8 * h;
#pragma unroll
      for (int k = 0; k < 4; ++k) {
        const unsigned v1 = (j1 == 2 * k) ? 0x00003F80u
                           : (j1 == 2 * k + 1) ? 0x3F800000u : 0u;
        const unsigned v2 = (j2 == 2 * k) ? 0x00003F80u
                           : (j2 == 2 * k + 1) ? 0x3F800000u : 0u;
        buA[k] = v1; buA[4 + k] = v2;
        buB[k] = v1; buB[4 + k] = v2;
      }
    }
    const f32x16 zf = {0.f, 0.f, 0.f, 0.f, 0.f, 0.f, 0.f, 0.f,
                       0.f, 0.f, 0.f, 0.f, 0.f, 0.f, 0.f, 0.f};
    f32x16 accA, accB;
    float offA = 0.0f, offB = 0.0f;

    // exact power-of-2 renorm (unchanged math)
    auto renorm = [&](f32x16& acc, float& off) {
      float mx = acc[0];
#pragma unroll
      for (int r = 1; r < 16; ++r) mx = fmaxf(mx, acc[r]);
#pragma unroll
      for (int d = 1; d < 64; d <<= 1) mx = fmaxf(mx, __shfl_xor(mx, d));
      const int e = (int)((__float_as_uint(mx) >> 23) & 255u);
      const float sc = __uint_as_float((unsigned)(254 - e) << 23);
#pragma unroll
      for (int r = 0; r < 16; ++r) acc[r] *= sc;
      off += (float)(e - 127) * LN2F;
    };

    // single-chain step (tail paths only)
    auto mm = [&](unsigned (&bu)[8], f32x16& acc, float& off, float f,
                  bool rn) {
      const float w = __expf(f);
      const f32x2 w2 = {w, w};
      BF8 A1, A2, B1, B2;
#pragma unroll
      for (int j = 0; j < 4; ++j) {
        const f32x2 p1 = e1[j] * w2;
        const f32x2 p2 = e2[j] * w2;
        A1.u[j] = pk2z(p1.x, p1.y);
        A2.u[j] = pk2z(p2.x, p2.y);
        B1.u[j] = bu[j];
        B2.u[j] = bu[4 + j];
      }
      acc = __builtin_amdgcn_mfma_f32_32x32x16_bf16(A2.v, B2.v, zf, 0, 0, 0);
      acc = __builtin_amdgcn_mfma_f32_32x32x16_bf16(A1.v, B1.v, acc, 0, 0, 0);
      if (rn) renorm(acc, off);
      unsigned qa = pk2z(acc[0], acc[1]);
      unsigned qb = pk2z(acc[2], acc[3]);
      unsigned qc = pk2z(acc[4], acc[5]);
      unsigned qd = pk2z(acc[6], acc[7]);
      unsigned qe = pk2z(acc[8], acc[9]);
      unsigned qf = pk2z(acc[10], acc[11]);
      unsigned qg = pk2z(acc[12], acc[13]);
      unsigned qh = pk2z(acc[14], acc[15]);
      plswap(qa, qc);
      plswap(qb, qd);
      plswap(qe, qg);
      plswap(qf, qh);
      bu[0] = qa; bu[1] = qb; bu[2] = qc; bu[3] = qd;
      bu[4] = qe; bu[5] = qf; bu[6] = qg; bu[7] = qh;
    };

    // dual-chain step: chains interleaved, ONE asm block for all 8 swaps.
    auto mm2 = [&](float fA, float fB, bool rn) {
      const float wA = __expf(fA);
      const float wB = __expf(fB);
      const f32x2 wA2 = {wA, wA};
      const f32x2 wB2 = {wB, wB};
      BF8 A1A, A2A, B1A, B2A, A1B, A2B, B1B, B2B;
#pragma unroll
      for (int j = 0; j < 4; ++j) {
        const f32x2 p1A = e1[j] * wA2;
        const f32x2 p2A = e2[j] * wA2;
        const f32x2 p1B = e1[j] * wB2;
        const f32x2 p2B = e2[j] * wB2;
        A1A.u[j] = pk2z(p1A.x, p1A.y);
        A2A.u[j] = pk2z(p2A.x, p2A.y);
        A1B.u[j] = pk2z(p1B.x, p1B.y);
        A2B.u[j] = pk2z(p2B.x, p2B.y);
        B1A.u[j] = buA[j];
        B2A.u[j] = buA[4 + j];
        B1B.u[j] = buB[j];
        B2B.u[j] = buB[4 + j];
      }
      // MFMAs interleaved: B's issue fills A's C-dependency window.
      accA = __builtin_amdgcn_mfma_f32_32x32x16_bf16(A2A.v, B2A.v, zf, 0, 0, 0);
      accB = __builtin_amdgcn_mfma_f32_32x32x16_bf16(A2B.v, B2B.v, zf, 0, 0, 0);
      accA = __builtin_amdgcn_mfma_f32_32x32x16_bf16(A1A.v, B1A.v, accA, 0, 0, 0);
      accB = __builtin_amdgcn_mfma_f32_32x32x16_bf16(A1B.v, B1B.v, accB, 0, 0, 0);

      if (rn) { renorm(accA, offA); renorm(accB, offB); }

      // packs (builtins, schedulable under the MFMA latencies), then one
      // asm block = one scheduling fence per dual-step instead of eight.
      unsigned qaA = pk2z(accA[0], accA[1]);
      unsigned qaB = pk2z(accB[0], accB[1]);
      unsigned qbA = pk2z(accA[2], accA[3]);
      unsigned qbB = pk2z(accB[2], accB[3]);
      unsigned qcA = pk2z(accA[4], accA[5]);
      unsigned qcB = pk2z(accB[4], accB[5]);
      unsigned qdA = pk2z(accA[6], accA[7]);
      unsigned qdB = pk2z(accB[6], accB[7]);
      unsigned qeA = pk2z(accA[8], accA[9]);
      unsigned qeB = pk2z(accB[8], accB[9]);
      unsigned qfA = pk2z(accA[10], accA[11]);
      unsigned qfB = pk2z(accB[10], accB[11]);
      unsigned qgA = pk2z(accA[12], accA[13]);
      unsigned qgB = pk2z(accB[12], accB[13]);
      unsigned qhA = pk2z(accA[14], accA[15]);
      unsigned qhB = pk2z(accB[14], accB[15]);
      asm("v_permlane32_swap_b32 %0, %1\n\t"
          "v_permlane32_swap_b32 %2, %3\n\t"
          "v_permlane32_swap_b32 %4, %5\n\t"
          "v_permlane32_swap_b32 %6, %7\n\t"
          "v_permlane32_swap_b32 %8, %9\n\t"
          "v_permlane32_swap_b32 %10, %11\n\t"
          "v_permlane32_swap_b32 %12, %13\n\t"
          "v_permlane32_swap_b32 %14, %15"
          : "+v"(qaA), "+v"(qcA), "+v"(qbA), "+v"(qdA),
            "+v"(qeA), "+v"(qgA), "+v"(qfA), "+v"(qhA),
            "+v"(qaB), "+v"(qcB), "+v"(qbB), "+v"(qdB),
            "+v"(qeB), "+v"(qgB), "+v"(qfB), "+v"(qhB));
      buA[0] = qaA; buA[1] = qbA; buA[2] = qcA; buA[3] = qdA;
      buA[4] = qeA; buA[5] = qfA; buA[6] = qgA; buA[7] = qhA;
      buB[0] = qaB; buB[1] = qbB; buB[2] = qcB; buB[3] = qdB;
      buB[4] = qeB; buB[5] = qfB; buB[6] = qgB; buB[7] = qhB;
    };

    const float* ga = feats + ((size_t)b * Tn + (size_t)c0 * CH) * Kn;
    const float* gb = ga + (size_t)CH * Kn;     // chunk c0+1 is contiguous
    float* myla = &lds[wid][0][0][0];
    float* mylb = &lds[wid][1][0][0];

    // prime quarter 0 (global -> reg -> LDS; wave-private, no barrier)
    {
      float4 v0 = *(const float4*)(ga + lane * 4);
      float4 v1 = *(const float4*)(ga + 256 + lane * 4);
      *(float4*)(myla + lane * 4) = v0;
      *(float4*)(myla + 256 + lane * 4) = v1;
      if (n1) {
        float4 w0 = *(const float4*)(gb + lane * 4);
        float4 w1 = *(const float4*)(gb + 256 + lane * 4);
        *(float4*)(mylb + lane * 4) = w0;
        *(float4*)(mylb + 256 + lane * 4) = w1;
      }
    }

    const int nq = (n0 + QS - 1) / QS;
    for (int q = 0; q < nq; ++q) {
      // issue next quarter's global loads EARLY
      const bool morea = (q + 1) * QS < n0;
      const bool moreb = (q + 1) * QS < n1;
      float4 na0, na1, nb0, nb1;
      if (morea) {
        const float* p = ga + (q + 1) * QF + lane * 4;
        na0 = *(const float4*)(p);
        na1 = *(const float4*)(p + 256);
      }
      if (moreb) {
        const float* p = gb + (q + 1) * QF + lane * 4;
        nb0 = *(const float4*)(p);
        nb1 = *(const float4*)(p + 256);
      }

      const float* la = myla + (q & 1) * QF;
      const float* lb = mylb + (q & 1) * QF;

      for (int s8 = 0; s8 < 2; ++s8) {
        const int base = q * QS + s8 * 8;
        if (base >= n0) break;
        const bool rn7 = ((base >> 3) & 3) == 3;   // renorm only at i==7 here
        float fa[8];
#pragma unroll
        for (int i = 0; i < 8; ++i) fa[i] = la[(s8 * 8 + i) * Kn + m];

        if (base + 8 <= n1) {
          // hot path: both chains full, interleaved dual-step
          float fb[8];
#pragma unroll
          for (int i = 0; i < 8; ++i) fb[i] = lb[(s8 * 8 + i) * Kn + m];
#pragma unroll
          for (int i = 0; i < 8; ++i) mm2(fa[i], fb[i], i == 7 && rn7);
        } else if (base < n1) {
          // A full (n1>0 => n0==128), B tail-predicated (B never renorms here)
          float fb[8];
#pragma unroll
          for (int i = 0; i < 8; ++i) fb[i] = lb[(s8 * 8 + i) * Kn + m];
#pragma unroll
          for (int i = 0; i < 8; ++i) {
            mm(buA, accA, offA, fa[i], i == 7 && rn7);
            if (base + i < n1) mm(buB, accB, offB, fb[i], false);
          }
        } else if (base + 8 <= n0) {
#pragma unroll
          for (int i = 0; i < 8; ++i)
            mm(buA, accA, offA, fa[i], i == 7 && rn7);
        } else {
#pragma unroll
          for (int i = 0; i < 8; ++i)
            if (base + i < n0) mm(buA, accA, offA, fa[i], false);
        }
      }

      // write next quarter to the other LDS buffers (write-late)
      if (morea) {
        float* nb = myla + ((q + 1) & 1) * QF;
        *(float4*)(nb + lane * 4) = na0;
        *(float4*)(nb + 256 + lane * 4) = na1;
      }
      if (moreb) {
        float* nb = mylb + ((q + 1) & 1) * QF;
        *(float4*)(nb + lane * 4) = nb0;
        *(float4*)(nb + 256 + lane * 4) = nb1;
      }
    }

    // store chunk products (f32, row-major) + log offsets
    {
      float* pm = pmats + (size_t)(b * NC + c0) * (Kn * Kn);
#pragma unroll
      for (int r = 0; r < 16; ++r) {
        const int row = (r & 3) + 8 * (r >> 2) + 4 * h;
        pm[row * Kn + m] = accA[r];
      }
      if (lane == 0) poffs[b * NC + c0] = offA + 7.0f * LN2F * (float)n0;
    }
    if (n1) {
      float* pm = pmats + (size_t)(b * NC + c0 + 1) * (Kn * Kn);
#pragma unroll
      for (int r = 0; r < 16; ++r) {
        const int row = (r & 3) + 8 * (r >> 2) + 4 * h;
        pm[row * Kn + m] = accB[r];
      }
      if (lane == 0) poffs[b * NC + c0 + 1] = offB + 7.0f * LN2F * (float)n1;
    }
  } else {
    // ------- gold partial sums: 4 waves/b, interleaved stride -------------
    const int b = blockIdx.x - MMB;
    const int len = lens[b];
    const int* tg = tags + (size_t)b * Tn;
    const float* fbp = feats + (size_t)b * Tn * Kn;
    float acc = 0.f;
    for (int tt = 64 * wid + lane; tt < len; tt += 256) {
      const int tag = tg[tt];
      const int prev = tt ? tg[tt - 1] : START;
      acc += fbp[(size_t)tt * Kn + tag] + trans[tag * Kn + prev];
      if (tt == len - 1) acc += trans[STOP * Kn + tag];
    }
#pragma unroll
    for (int msk = 32; msk >= 1; msk >>= 1) acc += __shfl_xor(acc, msk);
    if (lane == 0) gold_part[b * GP + wid] = acc;   // always written
  }
}

// ---------------------------------------------------------------------------
// Phase 2: one 256-thread block per batch row. All 4 waves stage the row's
// nc chunk matrices (<=64 KB) into LDS with an XOR-swizzled float4 layout,
// then wave 0 walks the serial chain from LDS. (Unchanged — passes.)
// ---------------------------------------------------------------------------
__device__ __forceinline__ float renorm_s(float& s, float off) {
  int e = (int)((__float_as_uint(s) >> 23) & 255u);
  e = max(e, __shfl_xor(e, 1));
  e = max(e, __shfl_xor(e, 2));
  e = max(e, __shfl_xor(e, 4));
  e = max(e, __shfl_xor(e, 8));
  e = max(e, __shfl_xor(e, 16));
  s *= __uint_as_float((unsigned)(254 - e) << 23);
  return off + (float)(e - 127) * LN2F;
}

__global__ __launch_bounds__(256, 2) void crf_apply(
    const float* __restrict__ trans, const int* __restrict__ lens,
    const float* __restrict__ pmats, const float* __restrict__ poffs,
    const float* __restrict__ gold_part, float* __restrict__ out) {
  __shared__ float4 smat[NC * 256];   // 64 KiB: NC matrices of 256 float4
  const int tid = threadIdx.x;
  const int b = blockIdx.x;
  const int len = lens[b];
  const int nc = (len + CH - 1) / CH;

  // stage: global float4 index qq = (c<<8)|(row<<3)|g  ->  slot with g ^= row&7
  const float4* gp = (const float4*)(pmats + (size_t)b * NC * (Kn * Kn));
  for (int qq = tid; qq < nc * 256; qq += 256) {
    const int row = (qq >> 3) & 31;
    const int g = qq & 7;
    smat[(qq & ~7) | (g ^ (row & 7))] = gp[qq];
  }
  __syncthreads();
  if (tid >= 64) return;              // waves 1-3 done (no later barriers)

  const int lane = tid;
  const int n = lane & 31;
  const int hb = (lane >> 5) * 16;    // 0 or 16
  const int g0 = hb >> 2;             // 0 or 4
  const int nsw = n & 7;
  float s = (n == START) ? 1.0f : 0.0f;
  float off = 0.0f;
  for (int c = 0; c < nc; ++c) {
    const float4* mr = &smat[(c << 8) | (n << 3)];
    const float4 p0 = mr[(g0 + 0) ^ nsw];
    const float4 p1 = mr[(g0 + 1) ^ nsw];
    const float4 p2 = mr[(g0 + 2) ^ nsw];
    const float4 p3 = mr[(g0 + 3) ^ nsw];
    float a0 = 0.f, a1 = 0.f, a2 = 0.f, a3 = 0.f;
    a0 = fmaf(bcast32(s, hb + 0), p0.x, a0);
    a0 = fmaf(bcast32(s, hb + 1), p0.y, a0);
    a0 = fmaf(bcast32(s, hb + 2), p0.z, a0);
    a0 = fmaf(bcast32(s, hb + 3), p0.w, a0);
    a1 = fmaf(bcast32(s, hb + 4), p1.x, a1);
    a1 = fmaf(bcast32(s, hb + 5), p1.y, a1);
    a1 = fmaf(bcast32(s, hb + 6), p1.z, a1);
    a1 = fmaf(bcast32(s, hb + 7), p1.w, a1);
    a2 = fmaf(bcast32(s, hb + 8), p2.x, a2);
    a2 = fmaf(bcast32(s, hb + 9), p2.y, a2);
    a2 = fmaf(bcast32(s, hb + 10), p2.z, a2);
    a2 = fmaf(bcast32(s, hb + 11), p2.w, a2);
    a3 = fmaf(bcast32(s, hb + 12), p3.x, a3);
    a3 = fmaf(bcast32(s, hb + 13), p3.y, a3);
    a3 = fmaf(bcast32(s, hb + 14), p3.z, a3);
    a3 = fmaf(bcast32(s, hb + 15), p3.w, a3);
    float p = (a0 + a1) + (a2 + a3);
    p += __shfl_xor(p, 32);
    s = p;
    off = renorm_s(s, off);
    off += poffs[b * NC + c];
  }
  const float es = __expf(trans[STOP * Kn + n]);
  float q = s * es;
#pragma unroll
  for (int d = 1; d < 32; d <<= 1) q += __shfl_xor(q, d);
  if (lane == 0) {
    const float fs = __logf(q) + off;
    float gs = 0.f;
#pragma unroll
    for (int gi = 0; gi < GP; ++gi) gs += gold_part[b * GP + gi];
    atomicAdd(out, (fs - gs) * (1.0f / (float)Bn));
  }
}

extern "C" void kernel_launch(void* const* d_in, const int* in_sizes, int n_in,
                              void* d_out, int out_size, void* d_ws, size_t ws_size,
                              hipStream_t stream) {
  const float* feats = (const float*)d_in[0];
  const float* trans = (const float*)d_in[1];
  const int* tags = (const int*)d_in[2];
  const int* lens = (const int*)d_in[3];

  // ws layout (floats): [Bn*GP gold][Bn*NC poffs][Bn*NC*1024 pmats]
  float* gold_part = (float*)d_ws;                 // 2048 floats
  float* poffs = gold_part + (size_t)Bn * GP;      // 8192 floats
  float* pmats = poffs + (size_t)Bn * NC;          // 16B-aligned (40960 B)

  hipMemsetAsync(d_out, 0, (size_t)out_size * sizeof(float), stream);
  crf_fused<<<MMB + GB, 256, 0, stream>>>(feats, trans, tags, lens, pmats,
                                          poffs, gold_part);
  crf_apply<<<Bn, 256, 0, stream>>>(trans, lens, pmats, poffs, gold_part,
                                    (float*)d_out);
}

// Round 8
// 246.454 us; speedup vs baseline: 1.0859x; 1.0859x over previous
//
#include <hip/hip_runtime.h>
#include <cstdint>
#include <cstddef>

#define Kn 32
#define Bn 512
#define Tn 2048
#define CH 128              // chunk length
#define NC (Tn / CH)        // 16 chunks per batch row
#define GP 4                // gold partials per batch row (1 per wave)
#define MMB (Bn * 4)        // 2048 mm blocks, A-MAJOR: bid = a*512 + b
#define GB  Bn              // 512 gold blocks, 4 waves each
#define START 30
#define STOP 31
#define LN2F 0.69314718055994530942f
#define QS 16               // steps per staged LDS quarter (16KB LDS/block)
#define QF (QS * Kn)        // 512 floats = 2 KiB per buffer

typedef __attribute__((ext_vector_type(8))) short bf16x8;   // 8 bf16 (4 VGPRs)
typedef __attribute__((ext_vector_type(16))) float f32x16;  // MFMA 32x32 accum
typedef __attribute__((ext_vector_type(2))) float f32x2;    // packed f32 pair

union BF8 { bf16x8 v; unsigned u[4]; };

// pack two non-negative f32 -> bf16x2, round-toward-zero: single v_perm.
__device__ __forceinline__ unsigned pk2z(float lo, float hi) {
  return __builtin_amdgcn_perm(__float_as_uint(hi), __float_as_uint(lo),
                               0x07060302u);
}

__device__ __forceinline__ float bcast32(float v, int idx) {
  return __shfl(v, idx, 32);
}

// v_permlane32_swap_b32: swaps a's lanes 32..63 with b's lanes 0..31.
__device__ __forceinline__ void plswap(unsigned& a, unsigned& b) {
  asm("v_permlane32_swap_b32 %0, %1" : "+v"(a), "+v"(b));
}

// ---------------------------------------------------------------------------
// Fused phase 1. ONE WAVE PER CHUNK, A-MAJOR BLOCK MAPPING.
// (R7 resubmit — container infra failure, not a kernel failure.)
// R6 post-mortem: VALUBusy pinned at ~30-33% across SIX structurally
// different rounds. Root cause is XCD load skew, not in-wave latency:
// with bid = 4b+a (R2/R3) the always-working a=0 blocks are bid%8 in {0,4}
// -> ALL long blocks land on XCDs 0 and 4 (round-robin bid%8 assignment).
// Those 64 CUs run VALU-saturated for ~68us while XCDs 3/7 idle; chip
// averages hid it. Dual-chain/asm-fusion rounds (R5/R6) had the same skew
// (g=0 -> even XCDs) -> identical times. Fix: bid = a*512 + b so
// XCD = b%8 -- every XCD gets all chunk-groups of 64 rows (load ~ +/-7%).
// Gold block for row b is bid 2048+b -> SAME XCD as its mm blocks -> its
// feat gathers hit that XCD's L2.
// Per-step math bit-identical to R2/R3 (renorm cadence t%32==31, pk2z-rtz,
// permlane swap): absmax 0.0 preserved.
// P_new = diag(exp(feat_t))*exp(trans) * P_old via 2x mfma_f32_32x32x16_bf16.
// D layout: row=(r&3)+8*(r>>2)+4h, col=lane&31.
// ---------------------------------------------------------------------------
__global__ __launch_bounds__(256, 6) void crf_fused(
    const float* __restrict__ feats, const float* __restrict__ trans,
    const int* __restrict__ tags, const int* __restrict__ lens,
    float* __restrict__ pmats, float* __restrict__ poffs,
    float* __restrict__ gold_part) {
  __shared__ float lds[4][2][QF];   // 16 KiB: per-wave double buffer
  const int wid = threadIdx.x >> 6;
  const int lane = threadIdx.x & 63;

  if (blockIdx.x < MMB) {
    const int a = blockIdx.x >> 9;                  // chunk group 0..3
    const int b = blockIdx.x & 511;                 // batch row -> XCD = b%8
    const int c = a * 4 + wid;                      // 0..15
    const int len = lens[b];
    const int nsteps = min(max(len - c * CH, 0), CH);
    if (nsteps == 0) return;

    const int m = lane & 31;
    const int h = lane >> 5;

    // E fragments (f32 pairs) with 2^-7 static renorm folded in.
    f32x2 e1[4], e2[4];
    {
      const float* tr = trans + m * Kn + 8 * h;
#pragma unroll
      for (int j = 0; j < 4; ++j) {
        e1[j] = (f32x2){__expf(tr[2 * j]) * 0.0078125f,
                        __expf(tr[2 * j + 1]) * 0.0078125f};
        e2[j] = (f32x2){__expf(tr[16 + 2 * j]) * 0.0078125f,
                        __expf(tr[16 + 2 * j + 1]) * 0.0078125f};
      }
    }
    // identity B-fragments, index-free init (bf16 1.0 = 0x3F80)
    unsigned bu[8];
    {
      const int j1 = m - 8 * h;
      const int j2 = m - 16 - 8 * h;
#pragma unroll
      for (int k = 0; k < 4; ++k) {
        bu[k] = (j1 == 2 * k) ? 0x00003F80u
                              : (j1 == 2 * k + 1) ? 0x3F800000u : 0u;
        bu[4 + k] = (j2 == 2 * k) ? 0x00003F80u
                                  : (j2 == 2 * k + 1) ? 0x3F800000u : 0u;
      }
    }
    const f32x16 zf = {0.f, 0.f, 0.f, 0.f, 0.f, 0.f, 0.f, 0.f,
                       0.f, 0.f, 0.f, 0.f, 0.f, 0.f, 0.f, 0.f};
    f32x16 acc;
    float off = 0.0f;

    auto mmstep = [&](float f, bool rn) {
      const float w = __expf(f);
      const f32x2 w2 = {w, w};
      BF8 A1, A2, B1, B2;
#pragma unroll
      for (int j = 0; j < 4; ++j) {
        const f32x2 p1 = e1[j] * w2;
        const f32x2 p2 = e2[j] * w2;
        A1.u[j] = pk2z(p1.x, p1.y);
        A2.u[j] = pk2z(p2.x, p2.y);
        B1.u[j] = bu[j];
        B2.u[j] = bu[4 + j];
      }
      acc = __builtin_amdgcn_mfma_f32_32x32x16_bf16(A2.v, B2.v, zf, 0, 0, 0);
      acc = __builtin_amdgcn_mfma_f32_32x32x16_bf16(A1.v, B1.v, acc, 0, 0, 0);

      if (rn) {  // exact power-of-2 renorm
        float mx = acc[0];
#pragma unroll
        for (int r = 1; r < 16; ++r) mx = fmaxf(mx, acc[r]);
#pragma unroll
        for (int d = 1; d < 64; d <<= 1) mx = fmaxf(mx, __shfl_xor(mx, d));
        const int e = (int)((__float_as_uint(mx) >> 23) & 255u);
        const float sc = __uint_as_float((unsigned)(254 - e) << 23);
#pragma unroll
        for (int r = 0; r < 16; ++r) acc[r] *= sc;
        off += (float)(e - 127) * LN2F;
      }

      // D (f32) -> B fragments (bf16): 4 permlane32_swap.
      unsigned qa = pk2z(acc[0], acc[1]);
      unsigned qb = pk2z(acc[2], acc[3]);
      unsigned qc = pk2z(acc[4], acc[5]);
      unsigned qd = pk2z(acc[6], acc[7]);
      unsigned qe = pk2z(acc[8], acc[9]);
      unsigned qf = pk2z(acc[10], acc[11]);
      unsigned qg = pk2z(acc[12], acc[13]);
      unsigned qh = pk2z(acc[14], acc[15]);
      plswap(qa, qc);
      plswap(qb, qd);
      plswap(qe, qg);
      plswap(qf, qh);
      bu[0] = qa; bu[1] = qb; bu[2] = qc; bu[3] = qd;
      bu[4] = qe; bu[5] = qf; bu[6] = qg; bu[7] = qh;
    };

    const float* gsrc = feats + ((size_t)b * Tn + (size_t)c * CH) * Kn;
    float* myl = &lds[wid][0][0];

    // prime quarter 0 (global -> reg -> LDS; wave-private, no barrier)
    {
      float4 v0 = *(const float4*)(gsrc + 0 * 256 + lane * 4);
      float4 v1 = *(const float4*)(gsrc + 1 * 256 + lane * 4);
      *(float4*)(myl + 0 * 256 + lane * 4) = v0;
      *(float4*)(myl + 1 * 256 + lane * 4) = v1;
    }

    const int nq = (nsteps + QS - 1) / QS;
    for (int q = 0; q < nq; ++q) {
      // issue next quarter's global loads EARLY (latency hides under compute)
      float4 nv0, nv1;
      const bool more = (q + 1 < nq);
      if (more) {
        const float* g = gsrc + (q + 1) * QF + lane * 4;
        nv0 = *(const float4*)(g + 0 * 256);
        nv1 = *(const float4*)(g + 1 * 256);
      }

      const float* lbuf = myl + (q & 1) * QF;
      const int ns = min(QS, nsteps - q * QS);
      const int nb = ns >> 3;
      int tq = 0;
      for (int s8 = 0; s8 < nb; ++s8) {
        float fr[8];
#pragma unroll
        for (int i = 0; i < 8; ++i) fr[i] = lbuf[(tq + i) * Kn + m];
#pragma unroll
        for (int i = 0; i < 8; ++i)
          mmstep(fr[i], ((q * QS + tq + i) & 31) == 31);
        tq += 8;
      }
      const int rem = ns & 7;   // nonzero only in the chunk tail (rn=false)
      if (rem) {
        float fr[8];
#pragma unroll
        for (int i = 0; i < 8; ++i) fr[i] = lbuf[min(tq + i, QS - 1) * Kn + m];
#pragma unroll
        for (int i = 0; i < 8; ++i)
          if (i < rem) mmstep(fr[i], false);
      }

      // write next quarter to the other LDS buffer (write-late)
      if (more) {
        float* nbuf = myl + ((q + 1) & 1) * QF;
        *(float4*)(nbuf + 0 * 256 + lane * 4) = nv0;
        *(float4*)(nbuf + 1 * 256 + lane * 4) = nv1;
      }
    }

    // store chunk product (f32, row-major) + log offset
    float* pm = pmats + (size_t)(b * NC + c) * (Kn * Kn);
#pragma unroll
    for (int r = 0; r < 16; ++r) {
      const int row = (r & 3) + 8 * (r >> 2) + 4 * h;
      pm[row * Kn + m] = acc[r];
    }
    if (lane == 0) poffs[b * NC + c] = off + 7.0f * LN2F * (float)nsteps;
  } else {
    // ------- gold partial sums: 4 waves/b, interleaved stride -------------
    // bid = MMB + b -> same XCD as row b's mm blocks (L2 reuse of feats)
    const int b = blockIdx.x - MMB;
    const int len = lens[b];
    const int* tg = tags + (size_t)b * Tn;
    const float* fbp = feats + (size_t)b * Tn * Kn;
    float acc = 0.f;
    for (int tt = 64 * wid + lane; tt < len; tt += 256) {
      const int tag = tg[tt];
      const int prev = tt ? tg[tt - 1] : START;
      acc += fbp[(size_t)tt * Kn + tag] + trans[tag * Kn + prev];
      if (tt == len - 1) acc += trans[STOP * Kn + tag];
    }
#pragma unroll
    for (int msk = 32; msk >= 1; msk >>= 1) acc += __shfl_xor(acc, msk);
    if (lane == 0) gold_part[b * GP + wid] = acc;   // always written
  }
}

// ---------------------------------------------------------------------------
// Phase 2: one 256-thread block per batch row. All 4 waves stage the row's
// nc chunk matrices (<=64 KB) into LDS with an XOR-swizzled float4 layout,
// then wave 0 walks the serial chain from LDS. (Unchanged — passes.)
// ---------------------------------------------------------------------------
__device__ __forceinline__ float renorm_s(float& s, float off) {
  int e = (int)((__float_as_uint(s) >> 23) & 255u);
  e = max(e, __shfl_xor(e, 1));
  e = max(e, __shfl_xor(e, 2));
  e = max(e, __shfl_xor(e, 4));
  e = max(e, __shfl_xor(e, 8));
  e = max(e, __shfl_xor(e, 16));
  s *= __uint_as_float((unsigned)(254 - e) << 23);
  return off + (float)(e - 127) * LN2F;
}

__global__ __launch_bounds__(256, 2) void crf_apply(
    const float* __restrict__ trans, const int* __restrict__ lens,
    const float* __restrict__ pmats, const float* __restrict__ poffs,
    const float* __restrict__ gold_part, float* __restrict__ out) {
  __shared__ float4 smat[NC * 256];   // 64 KiB: NC matrices of 256 float4
  const int tid = threadIdx.x;
  const int b = blockIdx.x;
  const int len = lens[b];
  const int nc = (len + CH - 1) / CH;

  // stage: global float4 index qq = (c<<8)|(row<<3)|g  ->  slot with g ^= row&7
  const float4* gp = (const float4*)(pmats + (size_t)b * NC * (Kn * Kn));
  for (int qq = tid; qq < nc * 256; qq += 256) {
    const int row = (qq >> 3) & 31;
    const int g = qq & 7;
    smat[(qq & ~7) | (g ^ (row & 7))] = gp[qq];
  }
  __syncthreads();
  if (tid >= 64) return;              // waves 1-3 done (no later barriers)

  const int lane = tid;
  const int n = lane & 31;
  const int hb = (lane >> 5) * 16;    // 0 or 16
  const int g0 = hb >> 2;             // 0 or 4
  const int nsw = n & 7;
  float s = (n == START) ? 1.0f : 0.0f;
  float off = 0.0f;
  for (int c = 0; c < nc; ++c) {
    const float4* mr = &smat[(c << 8) | (n << 3)];
    const float4 p0 = mr[(g0 + 0) ^ nsw];
    const float4 p1 = mr[(g0 + 1) ^ nsw];
    const float4 p2 = mr[(g0 + 2) ^ nsw];
    const float4 p3 = mr[(g0 + 3) ^ nsw];
    float a0 = 0.f, a1 = 0.f, a2 = 0.f, a3 = 0.f;
    a0 = fmaf(bcast32(s, hb + 0), p0.x, a0);
    a0 = fmaf(bcast32(s, hb + 1), p0.y, a0);
    a0 = fmaf(bcast32(s, hb + 2), p0.z, a0);
    a0 = fmaf(bcast32(s, hb + 3), p0.w, a0);
    a1 = fmaf(bcast32(s, hb + 4), p1.x, a1);
    a1 = fmaf(bcast32(s, hb + 5), p1.y, a1);
    a1 = fmaf(bcast32(s, hb + 6), p1.z, a1);
    a1 = fmaf(bcast32(s, hb + 7), p1.w, a1);
    a2 = fmaf(bcast32(s, hb + 8), p2.x, a2);
    a2 = fmaf(bcast32(s, hb + 9), p2.y, a2);
    a2 = fmaf(bcast32(s, hb + 10), p2.z, a2);
    a2 = fmaf(bcast32(s, hb + 11), p2.w, a2);
    a3 = fmaf(bcast32(s, hb + 12), p3.x, a3);
    a3 = fmaf(bcast32(s, hb + 13), p3.y, a3);
    a3 = fmaf(bcast32(s, hb + 14), p3.z, a3);
    a3 = fmaf(bcast32(s, hb + 15), p3.w, a3);
    float p = (a0 + a1) + (a2 + a3);
    p += __shfl_xor(p, 32);
    s = p;
    off = renorm_s(s, off);
    off += poffs[b * NC + c];
  }
  const float es = __expf(trans[STOP * Kn + n]);
  float q = s * es;
#pragma unroll
  for (int d = 1; d < 32; d <<= 1) q += __shfl_xor(q, d);
  if (lane == 0) {
    const float fs = __logf(q) + off;
    float gs = 0.f;
#pragma unroll
    for (int gi = 0; gi < GP; ++gi) gs += gold_part[b * GP + gi];
    atomicAdd(out, (fs - gs) * (1.0f / (float)Bn));
  }
}

extern "C" void kernel_launch(void* const* d_in, const int* in_sizes, int n_in,
                              void* d_out, int out_size, void* d_ws, size_t ws_size,
                              hipStream_t stream) {
  const float* feats = (const float*)d_in[0];
  const float* trans = (const float*)d_in[1];
  const int* tags = (const int*)d_in[2];
  const int* lens = (const int*)d_in[3];

  // ws layout (floats): [Bn*GP gold][Bn*NC poffs][Bn*NC*1024 pmats]
  float* gold_part = (float*)d_ws;                 // 2048 floats
  float* poffs = gold_part + (size_t)Bn * GP;      // 8192 floats
  float* pmats = poffs + (size_t)Bn * NC;          // 16B-aligned (40960 B)

  hipMemsetAsync(d_out, 0, (size_t)out_size * sizeof(float), stream);
  crf_fused<<<MMB + GB, 256, 0, stream>>>(feats, trans, tags, lens, pmats,
                                          poffs, gold_part);
  crf_apply<<<Bn, 256, 0, stream>>>(trans, lens, pmats, poffs, gold_part,
                                    (float*)d_out);
}